// Round 6
// baseline (126.305 us; speedup 1.0000x reference)
//
#include <hip/hip_runtime.h>
#include <math.h>

#define BB 64
#define QQ 600
#define NT 80
#define NC 92
#define SLOTS 10     // ceil(600/64)
#define NTILE 10     // 64-query tiles per batch
#define NTHR 256
#define NWAVE 4
#define MAXROUNDS 16 // Jacobi auction cap
#define STALLCAP 3   // break auction after 3 rounds with no new assignment
#define SPINCAP (1 << 20)
#define MAGIC 0x5A17C0DE

// ---------------------------------------------------------------------------
// R20 = R19 (62us measured) + ONE change: after the handshake, the solver
// block warms its local-XCD L2 with the full 192KB C panel (12000 float4
// loads, 8 in flight/thread, asm-sunk). Rationale: Phase-A wrote C from tile
// blocks on OTHER XCDs; per-XCD L2s are not cross-coherent, so every first
// touch of a row in the auction-rebid / Dijkstra-tree path pays ~500-900cy
// on the serial critical path (~70 cold rows x ~600cy ~= 17us of the ~25us
// drain). Prefetch costs ~1.2us and turns those into ~200cy local-L2 hits.
// Everything else R19-verbatim.
// ---------------------------------------------------------------------------

template <int CTRL>
__device__ __forceinline__ int dppi(int x) {
    return __builtin_amdgcn_update_dpp(x, x, CTRL, 0xF, 0xF, false);
}

// full-wave (64-lane) min of u32: 4x row_ror DPP (VALU) + xor16 swizzle + xor32
__device__ __forceinline__ unsigned wave_min_u32(unsigned x) {
    unsigned y;
    y = (unsigned)dppi<0x121>((int)x); x = x < y ? x : y;   // ror1
    y = (unsigned)dppi<0x122>((int)x); x = x < y ? x : y;   // ror2
    y = (unsigned)dppi<0x124>((int)x); x = x < y ? x : y;   // ror4
    y = (unsigned)dppi<0x128>((int)x); x = x < y ? x : y;   // ror8 -> row(16) min
    y = (unsigned)__builtin_amdgcn_ds_swizzle((int)x, 0x401F); x = x < y ? x : y; // xor16
    y = (unsigned)__shfl_xor((int)x, 32); x = x < y ? x : y;                      // xor32
    return x;
}

__device__ __forceinline__ unsigned long long u64min(unsigned long long a,
                                                     unsigned long long b) {
    return a < b ? a : b;
}

// full-wave min of u64 (two 32-bit halves per cross-lane move)
__device__ __forceinline__ unsigned long long wave_min_u64(unsigned long long x) {
    union U { unsigned long long v; int i[2]; };
    U c, o; c.v = x;
    o.i[0] = dppi<0x121>(c.i[0]); o.i[1] = dppi<0x121>(c.i[1]); c.v = u64min(c.v, o.v);
    o.i[0] = dppi<0x122>(c.i[0]); o.i[1] = dppi<0x122>(c.i[1]); c.v = u64min(c.v, o.v);
    o.i[0] = dppi<0x124>(c.i[0]); o.i[1] = dppi<0x124>(c.i[1]); c.v = u64min(c.v, o.v);
    o.i[0] = dppi<0x128>(c.i[0]); o.i[1] = dppi<0x128>(c.i[1]); c.v = u64min(c.v, o.v);
    o.i[0] = __builtin_amdgcn_ds_swizzle(c.i[0], 0x401F);
    o.i[1] = __builtin_amdgcn_ds_swizzle(c.i[1], 0x401F); c.v = u64min(c.v, o.v);
    o.i[0] = __shfl_xor(c.i[0], 32);
    o.i[1] = __shfl_xor(c.i[1], 32);                       c.v = u64min(c.v, o.v);
    return c.v;
}

// order-preserving bijections float<->u32, double<->u64 (no NaNs in data)
__device__ __forceinline__ unsigned f32_key(float f) {
    unsigned b = __float_as_uint(f);
    return b ^ ((unsigned)((int)b >> 31) | 0x80000000u);
}
__device__ __forceinline__ float key_f32(unsigned k) {
    unsigned b = (k & 0x80000000u) ? (k ^ 0x80000000u) : ~k;
    return __uint_as_float(b);
}
__device__ __forceinline__ unsigned long long f64_key(double d) {
    unsigned long long b = (unsigned long long)__double_as_longlong(d);
    return b ^ ((unsigned long long)((long long)b >> 63) | 0x8000000000000000ULL);
}
__device__ __forceinline__ double key_f64(unsigned long long k) {
    unsigned long long b = (k & 0x8000000000000000ULL) ? (k ^ 0x8000000000000000ULL) : ~k;
    return __longlong_as_double((long long)b);
}

__global__ __launch_bounds__(256) void matcher_kernel(
    const float* __restrict__ logits,   // (B,Q,NC)
    const float* __restrict__ pboxes,   // (B,Q,4)
    const int*   __restrict__ tlabels,  // (B,NT)
    const float* __restrict__ tboxes,   // (B,NT,4)
    float* __restrict__ cost,           // (B,NT,QQ) ws
    float* __restrict__ pm1,            // (B,NT,NTILE) ws
    float* __restrict__ pm2,            // (B,NT,NTILE) ws
    int*   __restrict__ pmj,            // (B,NT,NTILE) ws
    int*   __restrict__ done,           // (B*16) ws slots, NO init needed
    int* __restrict__ rows_out,         // (B,NT)
    int* __restrict__ cols_out)         // (B,NT)
{
    __shared__ float tile[64 * 93];
    __shared__ float s_pm[4 * 64], s_ps[4 * 64];
    __shared__ float s_tb[NT * 4];
    __shared__ int   s_tl[NT];
    // solver state (tix==0 block only)
    __shared__ double vA[QQ];
    __shared__ double u[NT];
    __shared__ double bidm1[NT], bidm2[NT];
    __shared__ int    bidj[NT], bidver[NT];
    __shared__ int    pA[QQ];
    __shared__ int    verA[QQ];
    __shared__ int    colrow[QQ];
    __shared__ int    assigned[NT];
    __shared__ int    plist[NT];
    __shared__ int    pcnt;
    __shared__ int    wayA[QQ];
    __shared__ int    c4r[NT];
    __shared__ int    djkA[NT];

    const int g   = blockIdx.x;
    const int b   = g / NTILE;
    const int tix = g % NTILE;
    const int tid = threadIdx.x;
    const int qq  = tid & 63;
    const int wv  = tid >> 6;           // 0..3
    const float* C = cost + (size_t)b * NT * QQ;

    // ================= Phase A: cost tile + partials =======================
    {
        const int q0 = tix * 64;
        const int nq = min(64, QQ - q0);   // 24 for the last tile
        const float* src = logits + ((size_t)b * QQ + q0) * NC;
        for (int idx = tid; idx < nq * NC; idx += 256) {
            const int r = idx / NC;
            tile[r * 93 + (idx - r * NC)] = src[idx];
        }
        for (int i = tid; i < NT * 4; i += 256) s_tb[i] = tboxes[b * NT * 4 + i];
        for (int i = tid; i < NT;     i += 256) s_tl[i] = tlabels[b * NT + i];
        __syncthreads();

        // R17 Phase-A stats: 4-way parallel; wave w owns cols [w*23, w*23+23).
        // Rows >= nq produce garbage stats (tile uninitialized) — never read.
        {
            const int c0 = wv * 23;
            const float* r = &tile[qq * 93];
            float pm = r[c0];
            #pragma unroll 11
            for (int c = 1; c < 23; ++c) pm = fmaxf(pm, r[c0 + c]);
            s_pm[wv * 64 + qq] = pm;
        }
        __syncthreads();
        {
            const int c0 = wv * 23;
            float* r = &tile[qq * 93];
            const float m = fmaxf(fmaxf(s_pm[qq], s_pm[64 + qq]),
                                  fmaxf(s_pm[128 + qq], s_pm[192 + qq]));
            float sum = 0.f;
            #pragma unroll 11
            for (int c = 0; c < 23; ++c) {
                const float e = expf(r[c0 + c] - m);
                r[c0 + c] = e;                  // exp written back into tile
                sum += e;
            }
            s_ps[wv * 64 + qq] = sum;
        }
        __syncthreads();

        const bool valid = qq < nq;
        float px1 = 0.f, py1 = 0.f, px2 = 0.f, py2 = 0.f, pa = 0.f, inv_s = 1.f;
        if (valid) {
            const float* pb = pboxes + ((size_t)b * QQ + q0 + qq) * 4;
            px1 = pb[0]; py1 = pb[1]; px2 = pb[2]; py2 = pb[3];
            pa  = (px2 - px1) * (py2 - py1);
            const float s = (s_ps[qq] + s_ps[64 + qq]) + (s_ps[128 + qq] + s_ps[192 + qq]);
            inv_s = 1.f / s;
        }
        float* crow = cost + (size_t)b * NT * QQ + q0 + qq;

        for (int tt = 0; tt < 20; ++tt) {
            const int t = wv * 20 + tt;
            float costv = INFINITY;
            if (valid) {
                const int lbl = s_tl[t];
                const float cc = -(tile[qq * 93 + lbl] * inv_s);  // exp precomputed
                const float tx1 = s_tb[t*4+0], ty1 = s_tb[t*4+1];
                const float tx2 = s_tb[t*4+2], ty2 = s_tb[t*4+3];
                const float cb = fabsf(px1-tx1) + fabsf(py1-ty1)
                               + fabsf(px2-tx2) + fabsf(py2-ty2);
                const float ta = (tx2 - tx1) * (ty2 - ty1);
                const float iw = fmaxf(fminf(px2, tx2) - fmaxf(px1, tx1), 0.f);
                const float ih = fmaxf(fminf(py2, ty2) - fmaxf(py1, ty1), 0.f);
                const float inter = iw * ih;
                const float uni   = pa + ta - inter;
                const float iou   = inter / uni;
                const float cw = fmaxf(fmaxf(px2, tx2) - fminf(px1, tx1), 0.f);
                const float ch = fmaxf(fmaxf(py2, ty2) - fminf(py1, ty1), 0.f);
                const float ac = cw * ch;
                const float giou = iou - (ac - uni) / ac;
                costv = (1.0f * cc + 5.0f * cb) + 2.0f * (-giou);
                crow[(size_t)t * QQ] = costv;
            }
            // DPP min-reduce on sortable keys + ballot argmin (R16-validated)
            const unsigned key  = f32_key(costv);          // INF for invalid lanes
            const unsigned kmin = wave_min_u32(key);
            const unsigned long long tied = __ballot(key == kmin);
            const int winlane = __builtin_ctzll(tied);
            const unsigned cand = (qq == winlane) ? 0xFFFFFFFFu : key;
            const unsigned k2   = wave_min_u32(cand);      // 2nd-min (dups kept)
            if (qq == 0) {
                const size_t idx = ((size_t)b * NT + t) * NTILE + tix;
                pm1[idx] = key_f32(kmin); pm2[idx] = key_f32(k2);
                pmj[idx] = q0 + winlane;
            }
        }
    }
    __syncthreads();      // all waves' global stores drained before release
    if (tid == 0)
        __hip_atomic_store(&done[b * 16 + tix], MAGIC, __ATOMIC_RELEASE, __HIP_MEMORY_SCOPE_AGENT);
    if (tix != 0) return;

    // ====== Handoff: threads 0..9 each acquire-spin on one tile slot =======
    if (tid < NTILE) {
        int spins = 0;
        while (__hip_atomic_load(&done[b * 16 + tid], __ATOMIC_ACQUIRE, __HIP_MEMORY_SCOPE_AGENT) != MAGIC) {
            __builtin_amdgcn_s_sleep(8);
            if (++spins > SPINCAP) break;   // hang guard (fails loudly)
        }
    }
    __syncthreads();

    // ---- R20: warm local-XCD L2 with this batch's full C panel (192 KB) ----
    // 12000 float4, 8 in flight per thread, empty-asm sink (no DCE, rule #17).
    {
        const int NF4 = NT * (QQ / 4);             // 12000
        const float4* p4 = (const float4*)C;
        for (int base = 0; base < NF4; base += 8 * NTHR) {
            float4 t0, t1, t2, t3, t4, t5, t6, t7;
            {
                const int i0 = min(base + 0*NTHR + tid, NF4-1); t0 = p4[i0];
                const int i1 = min(base + 1*NTHR + tid, NF4-1); t1 = p4[i1];
                const int i2 = min(base + 2*NTHR + tid, NF4-1); t2 = p4[i2];
                const int i3 = min(base + 3*NTHR + tid, NF4-1); t3 = p4[i3];
                const int i4 = min(base + 4*NTHR + tid, NF4-1); t4 = p4[i4];
                const int i5 = min(base + 5*NTHR + tid, NF4-1); t5 = p4[i5];
                const int i6 = min(base + 6*NTHR + tid, NF4-1); t6 = p4[i6];
                const int i7 = min(base + 7*NTHR + tid, NF4-1); t7 = p4[i7];
            }
            asm volatile("" :: "v"(t0.x), "v"(t0.w), "v"(t1.x), "v"(t1.w));
            asm volatile("" :: "v"(t2.x), "v"(t2.w), "v"(t3.x), "v"(t3.w));
            asm volatile("" :: "v"(t4.x), "v"(t4.w), "v"(t5.x), "v"(t5.w));
            asm volatile("" :: "v"(t6.x), "v"(t6.w), "v"(t7.x), "v"(t7.w));
        }
    }

    // ---- init solver state ----
    for (int c = tid; c < QQ; c += NTHR) { pA[c] = -1; verA[c] = 0; vA[c] = 0.0; }
    if (tid < NT) { assigned[tid] = 0; bidver[tid] = 0; }
    __syncthreads();

    // ---- combine tile partials -> full-row bids (R6 verbatim) ----
    if (tid < NT) {
        const int t = tid;
        const float* p1 = pm1 + ((size_t)b * NT + t) * NTILE;
        const float* p2 = pm2 + ((size_t)b * NT + t) * NTILE;
        const int*   pj = pmj + ((size_t)b * NT + t) * NTILE;
        float m1 = INFINITY, m2 = INFINITY; int j1 = QQ;
        for (int k = 0; k < NTILE; ++k) {       // ascending => first-occurrence
            const float a1 = p1[k], a2 = p2[k];
            const int   aj = pj[k];
            if (a1 < m1) { m2 = fminf(m1, a2); m1 = a1; j1 = aj; }
            else         { m2 = fminf(m2, a1); }
        }
        bidm1[t] = (double)m1; bidm2[t] = (double)m2; bidj[t] = j1;
        u[t] = (double)m1;      // feasible: keys only increase afterwards
    }
    __syncthreads();

    // ================= Jacobi parallel auction (R16 verbatim) ==============
    int prev_np = 0x7fffffff, stall = 0;
    for (int round = 0; round < MAXROUNDS; ++round) {
        for (int c = tid; c < QQ; c += NTHR) colrow[c] = 0x7fffffff;
        if (tid == 0) pcnt = 0;
        __syncthreads();
        if (tid < NT && !assigned[tid]) {
            const int j = bidj[tid];
            if (bidver[tid] == verA[j]) atomicMin(&colrow[j], tid);
        }
        __syncthreads();
        if (tid < NT && !assigned[tid]) {
            const int i = tid, j = bidj[i];
            if (bidver[i] == verA[j] && colrow[j] == i) {
                const double m1 = bidm1[i], m2 = bidm2[i];
                const int prev = pA[j];
                pA[j] = i;
                verA[j] = verA[j] + 1;
                vA[j] -= (m2 - m1);          // v only decreases (diff >= 0)
                u[i] = m2;
                assigned[i] = 1;
                if (prev >= 0) assigned[prev] = 0;
            }
        }
        __syncthreads();
        if (tid < NT && !assigned[tid]) { const int k = atomicAdd(&pcnt, 1); plist[k] = tid; }
        __syncthreads();
        const int np = pcnt;
        if (np == 0) break;
        if (np >= prev_np) { if (++stall >= STALLCAP) break; }
        else               { stall = 0; }
        prev_np = np;
        for (int idx = wv; idx < np; idx += NWAVE) {
            const int i = plist[idx];
            const float* rp = C + (size_t)i * QQ;
            float rowv[SLOTS];
            #pragma unroll
            for (int k = 0; k < SLOTS; ++k) { const int c = qq + 64*k; rowv[k] = (c < QQ) ? rp[c] : 0.f; }
            double m1 = INFINITY, m2 = INFINITY; int j1 = QQ;
            #pragma unroll
            for (int k = 0; k < SLOTS; ++k) {
                const int c = qq + 64 * k;
                if (c < QQ) {
                    const double key = (double)rowv[k] - vA[c];
                    if (key < m1)      { m2 = m1; m1 = key; j1 = c; }
                    else if (key < m2) { m2 = key; }
                }
            }
            const unsigned long long k1 = f64_key(m1);
            const unsigned long long kminv = wave_min_u64(k1);
            const unsigned long long tied = __ballot(k1 == kminv);
            const int winlane = __builtin_ctzll(tied);
            // global 2nd-min = min over (winner's m2, everyone else's m1)
            const unsigned long long c2 = (qq == winlane) ? f64_key(m2) : k1;
            const unsigned long long k2minv = wave_min_u64(c2);
            const int jwin = __shfl(j1, winlane);
            if (qq == 0) {
                bidm1[i] = key_f64(kminv); bidm2[i] = key_f64(k2minv); bidj[i] = jwin;
                bidver[i] = verA[jwin];
                u[i] = key_f64(kminv);       // feasible forever (v only dec.)
            }
        }
        __syncthreads();
    }

    if (wv != 0) return;   // ============ wave 0 only below; no barriers ====
    const int lane = qq;

    // collect drained rows (uniform control flow)
    int nd = 0;
    for (int i = 0; i < NT; ++i) {
        if (!assigned[i]) { if (lane == 0) djkA[nd] = i; ++nd; }
    }

    double v_[SLOTS], minv_[SLOTS];
    int p_[SLOTS];
    #pragma unroll
    for (int k = 0; k < SLOTS; ++k) {
        const int c = lane + 64 * k;
        v_[k] = (c < QQ) ? vA[c] : 0.0;
        p_[k] = (c < QQ) ? pA[c] : -1;
    }

    // ================= Dijkstra SAP (exact, R16 verbatim) ==================
    float rowv[SLOTS];
    for (int ii = 0; ii < nd; ++ii) {
        const int i = djkA[ii];
        #pragma unroll
        for (int k = 0; k < SLOTS; ++k) minv_[k] = INFINITY;
        unsigned usedm = 0;
        int j0 = -1;
        double ui0 = u[i];
        {
            const float* rp = C + (size_t)i * QQ;
            #pragma unroll
            for (int k = 0; k < SLOTS; ++k) { const int c = lane + 64*k; rowv[k] = (c < QQ) ? rp[c] : 0.f; }
        }
        int j1, i1;

        for (;;) {
            if (j0 >= 0 && (j0 & 63) == lane) usedm |= 1u << (j0 >> 6);

            double bestv = INFINITY; int bestc = QQ;
            #pragma unroll
            for (int k = 0; k < SLOTS; ++k) {
                const int c = lane + 64 * k;
                if (c < QQ && !((usedm >> k) & 1u)) {
                    const double cur = ((double)rowv[k] - ui0) - v_[k];
                    if (cur < minv_[k]) { minv_[k] = cur; wayA[c] = j0; }
                    if (minv_[k] < bestv) { bestv = minv_[k]; bestc = c; }
                }
            }
            const unsigned long long kb = f64_key(bestv);
            const unsigned long long kminv = wave_min_u64(kb);
            const unsigned long long tied = __ballot(kb == kminv);
            const int winlane = __builtin_ctzll(tied);
            const double delta = key_f64(kminv);
            j1 = __shfl(bestc, winlane);

            {   // i1 = p[j1] via register select + shuffle
                const int slot = j1 >> 6, lj = j1 & 63;
                int myp = p_[0];
                #pragma unroll
                for (int k = 1; k < SLOTS; ++k) if (slot == k) myp = p_[k];
                i1 = __shfl(myp, lj);
            }

            double ui_next = 0.0;
            float rown[SLOTS];
            if (i1 >= 0) {      // prefetch next row (not in tree -> u stable)
                ui_next = u[i1];
                const float* rp = C + (size_t)i1 * QQ;
                #pragma unroll
                for (int k = 0; k < SLOTS; ++k) { const int c = lane + 64*k; rown[k] = (c < QQ) ? rp[c] : 0.f; }
            }

            #pragma unroll
            for (int k = 0; k < SLOTS; ++k) {
                const int c = lane + 64 * k;
                if (c < QQ) {
                    if ((usedm >> k) & 1u) { v_[k] -= delta; u[p_[k]] += delta; }
                    else                     minv_[k] -= delta;
                }
            }
            if (lane == 0) u[i] += delta;

            j0 = j1;
            if (i1 < 0) break;
            ui0 = ui_next;
            #pragma unroll
            for (int k = 0; k < SLOTS; ++k) rowv[k] = rown[k];
        }

        if (lane == 0) {        // augment along way chain
            int jj = j1;
            while (jj >= 0) {
                const int pr = wayA[jj];
                pA[jj] = (pr < 0) ? i : pA[pr];
                jj = pr;
            }
        }
        #pragma unroll
        for (int k = 0; k < SLOTS; ++k) {
            const int c = lane + 64 * k;
            p_[k] = (c < QQ) ? pA[c] : -1;
        }
    }

    // ---- emit in increasing query order (== reference's stable argsort) ----
    #pragma unroll
    for (int k = 0; k < SLOTS; ++k) {
        const int c = lane + 64 * k;
        if (c < QQ) { const int t = pA[c]; if (t >= 0) c4r[t] = c; }
    }
    for (int t = lane; t < NT; t += 64) {
        const int c = c4r[t];
        int rank = 0;
        for (int t2 = 0; t2 < NT; ++t2) rank += (c4r[t2] < c) ? 1 : 0;
        rows_out[b * NT + rank] = c;
        cols_out[b * NT + rank] = t;
    }
}

extern "C" void kernel_launch(void* const* d_in, const int* in_sizes, int n_in,
                              void* d_out, int out_size, void* d_ws, size_t ws_size,
                              hipStream_t stream) {
    (void)in_sizes; (void)n_in; (void)out_size; (void)ws_size;
    const float* logits  = (const float*)d_in[0];
    const float* pboxes  = (const float*)d_in[1];
    const int*   tlabels = (const int*)d_in[2];
    const float* tboxes  = (const float*)d_in[3];
    float* cost = (float*)d_ws;                          // 12,288,000 B
    float* pm1  = cost + (size_t)BB * NT * QQ;           // +204,800 B
    float* pm2  = pm1  + (size_t)BB * NT * NTILE;        // +204,800 B
    int*   pmj  = (int*)(pm2 + (size_t)BB * NT * NTILE); // +204,800 B
    int*   done = pmj + (size_t)BB * NT * NTILE;         // +4,096 B (B*16 slots)
    int*   out  = (int*)d_out;

    // no memset: per-slot MAGIC handshake needs no initialization
    matcher_kernel<<<dim3(BB * NTILE), NTHR, 0, stream>>>(
        logits, pboxes, tlabels, tboxes, cost, pm1, pm2, pmj, done,
        out, out + BB * NT);
}

// Round 7
// 119.893 us; speedup vs baseline: 1.0535x; 1.0535x over previous
//
#include <hip/hip_runtime.h>
#include <math.h>

#define BB 64
#define QQ 600
#define NT 80
#define NC 92
#define SLOTS 10     // ceil(600/64)
#define NTILE 10     // 64-query tiles per batch
#define NTHR 256
#define NWAVE 4
#define MAXROUNDS 16 // Jacobi auction cap
#define STALLCAP 3   // break auction after 3 rounds with no new assignment
#define SPINCAP (1 << 20)
#define MAGIC 0x5A17C0DE

// ---------------------------------------------------------------------------
// R21 = R19 (62us best) + two-phase hi/lo u64 wave-min at the 3 solver reduce
// sites. R20 post-mortem: L2-warm prefetch regressed (+6us, FETCH +5MB) =>
// row-fetch latency is NOT the exposed term (fetch hides under update pass);
// the exposed serial chain is the reduce itself (~250-300cy of each ~600cy
// iteration: 6 dependent 2-word-compare steps, last two on the DS pipe).
// Two-phase: mhi = wave_min_u32(hi) (DPP-fused v_min_u32, ~100cy); unique-hi
// common case finishes with ballot + one 32-bit shfl; tie path does a second
// exact u32 reduce on lo among tied lanes — bit-exact, wave-uniform branch.
// R20 prefetch deleted. Everything else R19-verbatim.
// ---------------------------------------------------------------------------

template <int CTRL>
__device__ __forceinline__ int dppi(int x) {
    return __builtin_amdgcn_update_dpp(x, x, CTRL, 0xF, 0xF, false);
}

// full-wave (64-lane) min of u32: 4x row_ror DPP (VALU) + xor16 swizzle + xor32
__device__ __forceinline__ unsigned wave_min_u32(unsigned x) {
    unsigned y;
    y = (unsigned)dppi<0x121>((int)x); x = x < y ? x : y;   // ror1
    y = (unsigned)dppi<0x122>((int)x); x = x < y ? x : y;   // ror2
    y = (unsigned)dppi<0x124>((int)x); x = x < y ? x : y;   // ror4
    y = (unsigned)dppi<0x128>((int)x); x = x < y ? x : y;   // ror8 -> row(16) min
    y = (unsigned)__builtin_amdgcn_ds_swizzle((int)x, 0x401F); x = x < y ? x : y; // xor16
    y = (unsigned)__shfl_xor((int)x, 32); x = x < y ? x : y;                      // xor32
    return x;
}

// R21: exact 64-lane min of a u64 sortable key, two-phase (hi then lo).
// Returns min key; *winlane = lowest lane holding it (old tie semantics).
__device__ __forceinline__ unsigned long long wave_min_key64(
        unsigned long long key, int* winlane) {
    const unsigned hi = (unsigned)(key >> 32), lo = (unsigned)key;
    const unsigned mhi = wave_min_u32(hi);
    unsigned long long t = __ballot(hi == mhi);
    unsigned mlo;
    if (__popcll(t) > 1) {          // wave-uniform branch (t uniform)
        mlo = wave_min_u32((hi == mhi) ? lo : 0xFFFFFFFFu);
        t = __ballot(hi == mhi && lo == mlo);
    } else {
        mlo = (unsigned)__shfl((int)lo, __builtin_ctzll(t));
    }
    *winlane = __builtin_ctzll(t);
    return ((unsigned long long)mhi << 32) | mlo;
}

// min-value-only variant (no winlane needed)
__device__ __forceinline__ unsigned long long wave_min_key64_val(
        unsigned long long key) {
    const unsigned hi = (unsigned)(key >> 32), lo = (unsigned)key;
    const unsigned mhi = wave_min_u32(hi);
    const unsigned long long t = __ballot(hi == mhi);
    unsigned mlo;
    if (__popcll(t) > 1) mlo = wave_min_u32((hi == mhi) ? lo : 0xFFFFFFFFu);
    else                 mlo = (unsigned)__shfl((int)lo, __builtin_ctzll(t));
    return ((unsigned long long)mhi << 32) | mlo;
}

// order-preserving bijections float<->u32, double<->u64 (no NaNs in data)
__device__ __forceinline__ unsigned f32_key(float f) {
    unsigned b = __float_as_uint(f);
    return b ^ ((unsigned)((int)b >> 31) | 0x80000000u);
}
__device__ __forceinline__ float key_f32(unsigned k) {
    unsigned b = (k & 0x80000000u) ? (k ^ 0x80000000u) : ~k;
    return __uint_as_float(b);
}
__device__ __forceinline__ unsigned long long f64_key(double d) {
    unsigned long long b = (unsigned long long)__double_as_longlong(d);
    return b ^ ((unsigned long long)((long long)b >> 63) | 0x8000000000000000ULL);
}
__device__ __forceinline__ double key_f64(unsigned long long k) {
    unsigned long long b = (k & 0x8000000000000000ULL) ? (k ^ 0x8000000000000000ULL) : ~k;
    return __longlong_as_double((long long)b);
}

__global__ __launch_bounds__(256) void matcher_kernel(
    const float* __restrict__ logits,   // (B,Q,NC)
    const float* __restrict__ pboxes,   // (B,Q,4)
    const int*   __restrict__ tlabels,  // (B,NT)
    const float* __restrict__ tboxes,   // (B,NT,4)
    float* __restrict__ cost,           // (B,NT,QQ) ws
    float* __restrict__ pm1,            // (B,NT,NTILE) ws
    float* __restrict__ pm2,            // (B,NT,NTILE) ws
    int*   __restrict__ pmj,            // (B,NT,NTILE) ws
    int*   __restrict__ done,           // (B*16) ws slots, NO init needed
    int* __restrict__ rows_out,         // (B,NT)
    int* __restrict__ cols_out)         // (B,NT)
{
    __shared__ float tile[64 * 93];
    __shared__ float s_pm[4 * 64], s_ps[4 * 64];
    __shared__ float s_tb[NT * 4];
    __shared__ int   s_tl[NT];
    // solver state (tix==0 block only)
    __shared__ double vA[QQ];
    __shared__ double u[NT];
    __shared__ double bidm1[NT], bidm2[NT];
    __shared__ int    bidj[NT], bidver[NT];
    __shared__ int    pA[QQ];
    __shared__ int    verA[QQ];
    __shared__ int    colrow[QQ];
    __shared__ int    assigned[NT];
    __shared__ int    plist[NT];
    __shared__ int    pcnt;
    __shared__ int    wayA[QQ];
    __shared__ int    c4r[NT];
    __shared__ int    djkA[NT];

    const int g   = blockIdx.x;
    const int b   = g / NTILE;
    const int tix = g % NTILE;
    const int tid = threadIdx.x;
    const int qq  = tid & 63;
    const int wv  = tid >> 6;           // 0..3
    const float* C = cost + (size_t)b * NT * QQ;

    // ================= Phase A: cost tile + partials =======================
    {
        const int q0 = tix * 64;
        const int nq = min(64, QQ - q0);   // 24 for the last tile
        const float* src = logits + ((size_t)b * QQ + q0) * NC;
        for (int idx = tid; idx < nq * NC; idx += 256) {
            const int r = idx / NC;
            tile[r * 93 + (idx - r * NC)] = src[idx];
        }
        for (int i = tid; i < NT * 4; i += 256) s_tb[i] = tboxes[b * NT * 4 + i];
        for (int i = tid; i < NT;     i += 256) s_tl[i] = tlabels[b * NT + i];
        __syncthreads();

        // R17 Phase-A stats: 4-way parallel; wave w owns cols [w*23, w*23+23).
        // Rows >= nq produce garbage stats (tile uninitialized) — never read.
        {
            const int c0 = wv * 23;
            const float* r = &tile[qq * 93];
            float pm = r[c0];
            #pragma unroll 11
            for (int c = 1; c < 23; ++c) pm = fmaxf(pm, r[c0 + c]);
            s_pm[wv * 64 + qq] = pm;
        }
        __syncthreads();
        {
            const int c0 = wv * 23;
            float* r = &tile[qq * 93];
            const float m = fmaxf(fmaxf(s_pm[qq], s_pm[64 + qq]),
                                  fmaxf(s_pm[128 + qq], s_pm[192 + qq]));
            float sum = 0.f;
            #pragma unroll 11
            for (int c = 0; c < 23; ++c) {
                const float e = expf(r[c0 + c] - m);
                r[c0 + c] = e;                  // exp written back into tile
                sum += e;
            }
            s_ps[wv * 64 + qq] = sum;
        }
        __syncthreads();

        const bool valid = qq < nq;
        float px1 = 0.f, py1 = 0.f, px2 = 0.f, py2 = 0.f, pa = 0.f, inv_s = 1.f;
        if (valid) {
            const float* pb = pboxes + ((size_t)b * QQ + q0 + qq) * 4;
            px1 = pb[0]; py1 = pb[1]; px2 = pb[2]; py2 = pb[3];
            pa  = (px2 - px1) * (py2 - py1);
            const float s = (s_ps[qq] + s_ps[64 + qq]) + (s_ps[128 + qq] + s_ps[192 + qq]);
            inv_s = 1.f / s;
        }
        float* crow = cost + (size_t)b * NT * QQ + q0 + qq;

        for (int tt = 0; tt < 20; ++tt) {
            const int t = wv * 20 + tt;
            float costv = INFINITY;
            if (valid) {
                const int lbl = s_tl[t];
                const float cc = -(tile[qq * 93 + lbl] * inv_s);  // exp precomputed
                const float tx1 = s_tb[t*4+0], ty1 = s_tb[t*4+1];
                const float tx2 = s_tb[t*4+2], ty2 = s_tb[t*4+3];
                const float cb = fabsf(px1-tx1) + fabsf(py1-ty1)
                               + fabsf(px2-tx2) + fabsf(py2-ty2);
                const float ta = (tx2 - tx1) * (ty2 - ty1);
                const float iw = fmaxf(fminf(px2, tx2) - fmaxf(px1, tx1), 0.f);
                const float ih = fmaxf(fminf(py2, ty2) - fmaxf(py1, ty1), 0.f);
                const float inter = iw * ih;
                const float uni   = pa + ta - inter;
                const float iou   = inter / uni;
                const float cw = fmaxf(fmaxf(px2, tx2) - fminf(px1, tx1), 0.f);
                const float ch = fmaxf(fmaxf(py2, ty2) - fminf(py1, ty1), 0.f);
                const float ac = cw * ch;
                const float giou = iou - (ac - uni) / ac;
                costv = (1.0f * cc + 5.0f * cb) + 2.0f * (-giou);
                crow[(size_t)t * QQ] = costv;
            }
            // DPP min-reduce on sortable keys + ballot argmin (R16-validated)
            const unsigned key  = f32_key(costv);          // INF for invalid lanes
            const unsigned kmin = wave_min_u32(key);
            const unsigned long long tied = __ballot(key == kmin);
            const int winlane = __builtin_ctzll(tied);
            const unsigned cand = (qq == winlane) ? 0xFFFFFFFFu : key;
            const unsigned k2   = wave_min_u32(cand);      // 2nd-min (dups kept)
            if (qq == 0) {
                const size_t idx = ((size_t)b * NT + t) * NTILE + tix;
                pm1[idx] = key_f32(kmin); pm2[idx] = key_f32(k2);
                pmj[idx] = q0 + winlane;
            }
        }
    }
    __syncthreads();      // all waves' global stores drained before release
    if (tid == 0)
        __hip_atomic_store(&done[b * 16 + tix], MAGIC, __ATOMIC_RELEASE, __HIP_MEMORY_SCOPE_AGENT);
    if (tix != 0) return;

    // ====== Handoff: threads 0..9 each acquire-spin on one tile slot =======
    if (tid < NTILE) {
        int spins = 0;
        while (__hip_atomic_load(&done[b * 16 + tid], __ATOMIC_ACQUIRE, __HIP_MEMORY_SCOPE_AGENT) != MAGIC) {
            __builtin_amdgcn_s_sleep(8);
            if (++spins > SPINCAP) break;   // hang guard (fails loudly)
        }
    }
    __syncthreads();

    // ---- init solver state ----
    for (int c = tid; c < QQ; c += NTHR) { pA[c] = -1; verA[c] = 0; vA[c] = 0.0; }
    if (tid < NT) { assigned[tid] = 0; bidver[tid] = 0; }
    __syncthreads();

    // ---- combine tile partials -> full-row bids (R6 verbatim) ----
    if (tid < NT) {
        const int t = tid;
        const float* p1 = pm1 + ((size_t)b * NT + t) * NTILE;
        const float* p2 = pm2 + ((size_t)b * NT + t) * NTILE;
        const int*   pj = pmj + ((size_t)b * NT + t) * NTILE;
        float m1 = INFINITY, m2 = INFINITY; int j1 = QQ;
        for (int k = 0; k < NTILE; ++k) {       // ascending => first-occurrence
            const float a1 = p1[k], a2 = p2[k];
            const int   aj = pj[k];
            if (a1 < m1) { m2 = fminf(m1, a2); m1 = a1; j1 = aj; }
            else         { m2 = fminf(m2, a1); }
        }
        bidm1[t] = (double)m1; bidm2[t] = (double)m2; bidj[t] = j1;
        u[t] = (double)m1;      // feasible: keys only increase afterwards
    }
    __syncthreads();

    // ================= Jacobi parallel auction (R16 structure) =============
    int prev_np = 0x7fffffff, stall = 0;
    for (int round = 0; round < MAXROUNDS; ++round) {
        for (int c = tid; c < QQ; c += NTHR) colrow[c] = 0x7fffffff;
        if (tid == 0) pcnt = 0;
        __syncthreads();
        if (tid < NT && !assigned[tid]) {
            const int j = bidj[tid];
            if (bidver[tid] == verA[j]) atomicMin(&colrow[j], tid);
        }
        __syncthreads();
        if (tid < NT && !assigned[tid]) {
            const int i = tid, j = bidj[i];
            if (bidver[i] == verA[j] && colrow[j] == i) {
                const double m1 = bidm1[i], m2 = bidm2[i];
                const int prev = pA[j];
                pA[j] = i;
                verA[j] = verA[j] + 1;
                vA[j] -= (m2 - m1);          // v only decreases (diff >= 0)
                u[i] = m2;
                assigned[i] = 1;
                if (prev >= 0) assigned[prev] = 0;
            }
        }
        __syncthreads();
        if (tid < NT && !assigned[tid]) { const int k = atomicAdd(&pcnt, 1); plist[k] = tid; }
        __syncthreads();
        const int np = pcnt;
        if (np == 0) break;
        if (np >= prev_np) { if (++stall >= STALLCAP) break; }
        else               { stall = 0; }
        prev_np = np;
        for (int idx = wv; idx < np; idx += NWAVE) {
            const int i = plist[idx];
            const float* rp = C + (size_t)i * QQ;
            float rowv[SLOTS];
            #pragma unroll
            for (int k = 0; k < SLOTS; ++k) { const int c = qq + 64*k; rowv[k] = (c < QQ) ? rp[c] : 0.f; }
            double m1 = INFINITY, m2 = INFINITY; int j1 = QQ;
            #pragma unroll
            for (int k = 0; k < SLOTS; ++k) {
                const int c = qq + 64 * k;
                if (c < QQ) {
                    const double key = (double)rowv[k] - vA[c];
                    if (key < m1)      { m2 = m1; m1 = key; j1 = c; }
                    else if (key < m2) { m2 = key; }
                }
            }
            // R21: two-phase hi/lo reduce (exact) replaces wave_min_u64
            int winlane;
            const unsigned long long kminv = wave_min_key64(f64_key(m1), &winlane);
            // global 2nd-min = min over (winner's m2, everyone else's m1)
            const unsigned long long c2 = (qq == winlane) ? f64_key(m2) : f64_key(m1);
            const unsigned long long k2minv = wave_min_key64_val(c2);
            const int jwin = __shfl(j1, winlane);
            if (qq == 0) {
                bidm1[i] = key_f64(kminv); bidm2[i] = key_f64(k2minv); bidj[i] = jwin;
                bidver[i] = verA[jwin];
                u[i] = key_f64(kminv);       // feasible forever (v only dec.)
            }
        }
        __syncthreads();
    }

    if (wv != 0) return;   // ============ wave 0 only below; no barriers ====
    const int lane = qq;

    // collect drained rows (uniform control flow)
    int nd = 0;
    for (int i = 0; i < NT; ++i) {
        if (!assigned[i]) { if (lane == 0) djkA[nd] = i; ++nd; }
    }

    double v_[SLOTS], minv_[SLOTS];
    int p_[SLOTS];
    #pragma unroll
    for (int k = 0; k < SLOTS; ++k) {
        const int c = lane + 64 * k;
        v_[k] = (c < QQ) ? vA[c] : 0.0;
        p_[k] = (c < QQ) ? pA[c] : -1;
    }

    // ================= Dijkstra SAP (exact, R16 structure) =================
    float rowv[SLOTS];
    for (int ii = 0; ii < nd; ++ii) {
        const int i = djkA[ii];
        #pragma unroll
        for (int k = 0; k < SLOTS; ++k) minv_[k] = INFINITY;
        unsigned usedm = 0;
        int j0 = -1;
        double ui0 = u[i];
        {
            const float* rp = C + (size_t)i * QQ;
            #pragma unroll
            for (int k = 0; k < SLOTS; ++k) { const int c = lane + 64*k; rowv[k] = (c < QQ) ? rp[c] : 0.f; }
        }
        int j1, i1;

        for (;;) {
            if (j0 >= 0 && (j0 & 63) == lane) usedm |= 1u << (j0 >> 6);

            double bestv = INFINITY; int bestc = QQ;
            #pragma unroll
            for (int k = 0; k < SLOTS; ++k) {
                const int c = lane + 64 * k;
                if (c < QQ && !((usedm >> k) & 1u)) {
                    const double cur = ((double)rowv[k] - ui0) - v_[k];
                    if (cur < minv_[k]) { minv_[k] = cur; wayA[c] = j0; }
                    if (minv_[k] < bestv) { bestv = minv_[k]; bestc = c; }
                }
            }
            // R21: two-phase hi/lo reduce (exact) replaces wave_min_u64
            int winlane;
            const unsigned long long kminv = wave_min_key64(f64_key(bestv), &winlane);
            const double delta = key_f64(kminv);
            j1 = __shfl(bestc, winlane);

            {   // i1 = p[j1] via register select + shuffle
                const int slot = j1 >> 6, lj = j1 & 63;
                int myp = p_[0];
                #pragma unroll
                for (int k = 1; k < SLOTS; ++k) if (slot == k) myp = p_[k];
                i1 = __shfl(myp, lj);
            }

            double ui_next = 0.0;
            float rown[SLOTS];
            if (i1 >= 0) {      // prefetch next row (not in tree -> u stable)
                ui_next = u[i1];
                const float* rp = C + (size_t)i1 * QQ;
                #pragma unroll
                for (int k = 0; k < SLOTS; ++k) { const int c = lane + 64*k; rown[k] = (c < QQ) ? rp[c] : 0.f; }
            }

            #pragma unroll
            for (int k = 0; k < SLOTS; ++k) {
                const int c = lane + 64 * k;
                if (c < QQ) {
                    if ((usedm >> k) & 1u) { v_[k] -= delta; u[p_[k]] += delta; }
                    else                     minv_[k] -= delta;
                }
            }
            if (lane == 0) u[i] += delta;

            j0 = j1;
            if (i1 < 0) break;
            ui0 = ui_next;
            #pragma unroll
            for (int k = 0; k < SLOTS; ++k) rowv[k] = rown[k];
        }

        if (lane == 0) {        // augment along way chain
            int jj = j1;
            while (jj >= 0) {
                const int pr = wayA[jj];
                pA[jj] = (pr < 0) ? i : pA[pr];
                jj = pr;
            }
        }
        #pragma unroll
        for (int k = 0; k < SLOTS; ++k) {
            const int c = lane + 64 * k;
            p_[k] = (c < QQ) ? pA[c] : -1;
        }
    }

    // ---- emit in increasing query order (== reference's stable argsort) ----
    #pragma unroll
    for (int k = 0; k < SLOTS; ++k) {
        const int c = lane + 64 * k;
        if (c < QQ) { const int t = pA[c]; if (t >= 0) c4r[t] = c; }
    }
    for (int t = lane; t < NT; t += 64) {
        const int c = c4r[t];
        int rank = 0;
        for (int t2 = 0; t2 < NT; ++t2) rank += (c4r[t2] < c) ? 1 : 0;
        rows_out[b * NT + rank] = c;
        cols_out[b * NT + rank] = t;
    }
}

extern "C" void kernel_launch(void* const* d_in, const int* in_sizes, int n_in,
                              void* d_out, int out_size, void* d_ws, size_t ws_size,
                              hipStream_t stream) {
    (void)in_sizes; (void)n_in; (void)out_size; (void)ws_size;
    const float* logits  = (const float*)d_in[0];
    const float* pboxes  = (const float*)d_in[1];
    const int*   tlabels = (const int*)d_in[2];
    const float* tboxes  = (const float*)d_in[3];
    float* cost = (float*)d_ws;                          // 12,288,000 B
    float* pm1  = cost + (size_t)BB * NT * QQ;           // +204,800 B
    float* pm2  = pm1  + (size_t)BB * NT * NTILE;        // +204,800 B
    int*   pmj  = (int*)(pm2 + (size_t)BB * NT * NTILE); // +204,800 B
    int*   done = pmj + (size_t)BB * NT * NTILE;         // +4,096 B (B*16 slots)
    int*   out  = (int*)d_out;

    // no memset: per-slot MAGIC handshake needs no initialization
    matcher_kernel<<<dim3(BB * NTILE), NTHR, 0, stream>>>(
        logits, pboxes, tlabels, tboxes, cost, pm1, pm2, pmj, done,
        out, out + BB * NT);
}

// Round 9
// 107.566 us; speedup vs baseline: 1.1742x; 1.1146x over previous
//
#include <hip/hip_runtime.h>
#include <math.h>

#define BB 64
#define QQ 600
#define NT 80
#define NC 92
#define SLOTS 10     // ceil(600/64)
#define NTILE 10     // 64-query tiles per batch
#define NTHR 256
#define NWAVE 4
#define MAXROUNDS 16 // Jacobi auction cap
#define STALLCAP 3   // break auction after 3 rounds with no new assignment

// ---------------------------------------------------------------------------
// R23 == R22 resubmission (R8 bench failed on container acquire — same infra
// error string as R3, which ran clean on verbatim resubmit; kernel audited:
// no sync/alloc calls, all loops bounded, barriers uniform, indices in range).
// R22: MEASUREMENT ROUND. Split the fused kernel into two dispatches so
// rocprof reports each phase's dur_us directly:
//   kernel A (640 blocks): Phase A verbatim -> cost + pm1/pm2/pmj.
//   kernel B (64 blocks):  solver verbatim (init/combine/auction/drain/emit).
// Same-stream ordering replaces the MAGIC handshake (kernel boundary is the
// architectural cross-XCD coherence point). Predicted ~neutral total;
// the per-dispatch split decides where the remaining rounds go.
// ---------------------------------------------------------------------------

template <int CTRL>
__device__ __forceinline__ int dppi(int x) {
    return __builtin_amdgcn_update_dpp(x, x, CTRL, 0xF, 0xF, false);
}

// full-wave (64-lane) min of u32: 4x row_ror DPP (VALU) + xor16 swizzle + xor32
__device__ __forceinline__ unsigned wave_min_u32(unsigned x) {
    unsigned y;
    y = (unsigned)dppi<0x121>((int)x); x = x < y ? x : y;   // ror1
    y = (unsigned)dppi<0x122>((int)x); x = x < y ? x : y;   // ror2
    y = (unsigned)dppi<0x124>((int)x); x = x < y ? x : y;   // ror4
    y = (unsigned)dppi<0x128>((int)x); x = x < y ? x : y;   // ror8 -> row(16) min
    y = (unsigned)__builtin_amdgcn_ds_swizzle((int)x, 0x401F); x = x < y ? x : y; // xor16
    y = (unsigned)__shfl_xor((int)x, 32); x = x < y ? x : y;                      // xor32
    return x;
}

// exact 64-lane min of a u64 sortable key, two-phase (hi then lo).
// Returns min key; *winlane = lowest lane holding it (old tie semantics).
__device__ __forceinline__ unsigned long long wave_min_key64(
        unsigned long long key, int* winlane) {
    const unsigned hi = (unsigned)(key >> 32), lo = (unsigned)key;
    const unsigned mhi = wave_min_u32(hi);
    unsigned long long t = __ballot(hi == mhi);
    unsigned mlo;
    if (__popcll(t) > 1) {          // wave-uniform branch (t uniform)
        mlo = wave_min_u32((hi == mhi) ? lo : 0xFFFFFFFFu);
        t = __ballot(hi == mhi && lo == mlo);
    } else {
        mlo = (unsigned)__shfl((int)lo, __builtin_ctzll(t));
    }
    *winlane = __builtin_ctzll(t);
    return ((unsigned long long)mhi << 32) | mlo;
}

// min-value-only variant (no winlane needed)
__device__ __forceinline__ unsigned long long wave_min_key64_val(
        unsigned long long key) {
    const unsigned hi = (unsigned)(key >> 32), lo = (unsigned)key;
    const unsigned mhi = wave_min_u32(hi);
    const unsigned long long t = __ballot(hi == mhi);
    unsigned mlo;
    if (__popcll(t) > 1) mlo = wave_min_u32((hi == mhi) ? lo : 0xFFFFFFFFu);
    else                 mlo = (unsigned)__shfl((int)lo, __builtin_ctzll(t));
    return ((unsigned long long)mhi << 32) | mlo;
}

// order-preserving bijections float<->u32, double<->u64 (no NaNs in data)
__device__ __forceinline__ unsigned f32_key(float f) {
    unsigned b = __float_as_uint(f);
    return b ^ ((unsigned)((int)b >> 31) | 0x80000000u);
}
__device__ __forceinline__ float key_f32(unsigned k) {
    unsigned b = (k & 0x80000000u) ? (k ^ 0x80000000u) : ~k;
    return __uint_as_float(b);
}
__device__ __forceinline__ unsigned long long f64_key(double d) {
    unsigned long long b = (unsigned long long)__double_as_longlong(d);
    return b ^ ((unsigned long long)((long long)b >> 63) | 0x8000000000000000ULL);
}
__device__ __forceinline__ double key_f64(unsigned long long k) {
    unsigned long long b = (k & 0x8000000000000000ULL) ? (k ^ 0x8000000000000000ULL) : ~k;
    return __longlong_as_double((long long)b);
}

// ============================ Kernel A: Phase A =============================
__global__ __launch_bounds__(256) void phasea_kernel(
    const float* __restrict__ logits,   // (B,Q,NC)
    const float* __restrict__ pboxes,   // (B,Q,4)
    const int*   __restrict__ tlabels,  // (B,NT)
    const float* __restrict__ tboxes,   // (B,NT,4)
    float* __restrict__ cost,           // (B,NT,QQ) ws
    float* __restrict__ pm1,            // (B,NT,NTILE) ws
    float* __restrict__ pm2,            // (B,NT,NTILE) ws
    int*   __restrict__ pmj)            // (B,NT,NTILE) ws
{
    __shared__ float tile[64 * 93];
    __shared__ float s_pm[4 * 64], s_ps[4 * 64];
    __shared__ float s_tb[NT * 4];
    __shared__ int   s_tl[NT];

    const int g   = blockIdx.x;
    const int b   = g / NTILE;
    const int tix = g % NTILE;
    const int tid = threadIdx.x;
    const int qq  = tid & 63;
    const int wv  = tid >> 6;           // 0..3

    const int q0 = tix * 64;
    const int nq = min(64, QQ - q0);   // 24 for the last tile
    const float* src = logits + ((size_t)b * QQ + q0) * NC;
    for (int idx = tid; idx < nq * NC; idx += 256) {
        const int r = idx / NC;
        tile[r * 93 + (idx - r * NC)] = src[idx];
    }
    for (int i = tid; i < NT * 4; i += 256) s_tb[i] = tboxes[b * NT * 4 + i];
    for (int i = tid; i < NT;     i += 256) s_tl[i] = tlabels[b * NT + i];
    __syncthreads();

    // 4-way parallel softmax stats; wave w owns cols [w*23, w*23+23).
    {
        const int c0 = wv * 23;
        const float* r = &tile[qq * 93];
        float pm = r[c0];
        #pragma unroll 11
        for (int c = 1; c < 23; ++c) pm = fmaxf(pm, r[c0 + c]);
        s_pm[wv * 64 + qq] = pm;
    }
    __syncthreads();
    {
        const int c0 = wv * 23;
        float* r = &tile[qq * 93];
        const float m = fmaxf(fmaxf(s_pm[qq], s_pm[64 + qq]),
                              fmaxf(s_pm[128 + qq], s_pm[192 + qq]));
        float sum = 0.f;
        #pragma unroll 11
        for (int c = 0; c < 23; ++c) {
            const float e = expf(r[c0 + c] - m);
            r[c0 + c] = e;                  // exp written back into tile
            sum += e;
        }
        s_ps[wv * 64 + qq] = sum;
    }
    __syncthreads();

    const bool valid = qq < nq;
    float px1 = 0.f, py1 = 0.f, px2 = 0.f, py2 = 0.f, pa = 0.f, inv_s = 1.f;
    if (valid) {
        const float* pb = pboxes + ((size_t)b * QQ + q0 + qq) * 4;
        px1 = pb[0]; py1 = pb[1]; px2 = pb[2]; py2 = pb[3];
        pa  = (px2 - px1) * (py2 - py1);
        const float s = (s_ps[qq] + s_ps[64 + qq]) + (s_ps[128 + qq] + s_ps[192 + qq]);
        inv_s = 1.f / s;
    }
    float* crow = cost + (size_t)b * NT * QQ + q0 + qq;

    for (int tt = 0; tt < 20; ++tt) {
        const int t = wv * 20 + tt;
        float costv = INFINITY;
        if (valid) {
            const int lbl = s_tl[t];
            const float cc = -(tile[qq * 93 + lbl] * inv_s);  // exp precomputed
            const float tx1 = s_tb[t*4+0], ty1 = s_tb[t*4+1];
            const float tx2 = s_tb[t*4+2], ty2 = s_tb[t*4+3];
            const float cb = fabsf(px1-tx1) + fabsf(py1-ty1)
                           + fabsf(px2-tx2) + fabsf(py2-ty2);
            const float ta = (tx2 - tx1) * (ty2 - ty1);
            const float iw = fmaxf(fminf(px2, tx2) - fmaxf(px1, tx1), 0.f);
            const float ih = fmaxf(fminf(py2, ty2) - fmaxf(py1, ty1), 0.f);
            const float inter = iw * ih;
            const float uni   = pa + ta - inter;
            const float iou   = inter / uni;
            const float cw = fmaxf(fmaxf(px2, tx2) - fminf(px1, tx1), 0.f);
            const float ch = fmaxf(fmaxf(py2, ty2) - fminf(py1, ty1), 0.f);
            const float ac = cw * ch;
            const float giou = iou - (ac - uni) / ac;
            costv = (1.0f * cc + 5.0f * cb) + 2.0f * (-giou);
            crow[(size_t)t * QQ] = costv;
        }
        // DPP min-reduce on sortable keys + ballot argmin (R16-validated)
        const unsigned key  = f32_key(costv);          // INF for invalid lanes
        const unsigned kmin = wave_min_u32(key);
        const unsigned long long tied = __ballot(key == kmin);
        const int winlane = __builtin_ctzll(tied);
        const unsigned cand = (qq == winlane) ? 0xFFFFFFFFu : key;
        const unsigned k2   = wave_min_u32(cand);      // 2nd-min (dups kept)
        if (qq == 0) {
            const size_t idx = ((size_t)b * NT + t) * NTILE + tix;
            pm1[idx] = key_f32(kmin); pm2[idx] = key_f32(k2);
            pmj[idx] = q0 + winlane;
        }
    }
}

// ============================ Kernel B: solver ==============================
__global__ __launch_bounds__(256) void solver_kernel(
    const float* __restrict__ cost,     // (B,NT,QQ) ws
    const float* __restrict__ pm1,      // (B,NT,NTILE) ws
    const float* __restrict__ pm2,      // (B,NT,NTILE) ws
    const int*   __restrict__ pmj,      // (B,NT,NTILE) ws
    int* __restrict__ rows_out,         // (B,NT)
    int* __restrict__ cols_out)         // (B,NT)
{
    __shared__ double vA[QQ];
    __shared__ double u[NT];
    __shared__ double bidm1[NT], bidm2[NT];
    __shared__ int    bidj[NT], bidver[NT];
    __shared__ int    pA[QQ];
    __shared__ int    verA[QQ];
    __shared__ int    colrow[QQ];
    __shared__ int    assigned[NT];
    __shared__ int    plist[NT];
    __shared__ int    pcnt;
    __shared__ int    wayA[QQ];
    __shared__ int    c4r[NT];
    __shared__ int    djkA[NT];

    const int b   = blockIdx.x;
    const int tid = threadIdx.x;
    const int qq  = tid & 63;
    const int wv  = tid >> 6;           // 0..3
    const float* C = cost + (size_t)b * NT * QQ;

    // ---- init solver state ----
    for (int c = tid; c < QQ; c += NTHR) { pA[c] = -1; verA[c] = 0; vA[c] = 0.0; }
    if (tid < NT) { assigned[tid] = 0; bidver[tid] = 0; }
    __syncthreads();

    // ---- combine tile partials -> full-row bids (R6 verbatim) ----
    if (tid < NT) {
        const int t = tid;
        const float* p1 = pm1 + ((size_t)b * NT + t) * NTILE;
        const float* p2 = pm2 + ((size_t)b * NT + t) * NTILE;
        const int*   pj = pmj + ((size_t)b * NT + t) * NTILE;
        float m1 = INFINITY, m2 = INFINITY; int j1 = QQ;
        for (int k = 0; k < NTILE; ++k) {       // ascending => first-occurrence
            const float a1 = p1[k], a2 = p2[k];
            const int   aj = pj[k];
            if (a1 < m1) { m2 = fminf(m1, a2); m1 = a1; j1 = aj; }
            else         { m2 = fminf(m2, a1); }
        }
        bidm1[t] = (double)m1; bidm2[t] = (double)m2; bidj[t] = j1;
        u[t] = (double)m1;      // feasible: keys only increase afterwards
    }
    __syncthreads();

    // ================= Jacobi parallel auction (R16 structure) =============
    int prev_np = 0x7fffffff, stall = 0;
    for (int round = 0; round < MAXROUNDS; ++round) {
        for (int c = tid; c < QQ; c += NTHR) colrow[c] = 0x7fffffff;
        if (tid == 0) pcnt = 0;
        __syncthreads();
        if (tid < NT && !assigned[tid]) {
            const int j = bidj[tid];
            if (bidver[tid] == verA[j]) atomicMin(&colrow[j], tid);
        }
        __syncthreads();
        if (tid < NT && !assigned[tid]) {
            const int i = tid, j = bidj[i];
            if (bidver[i] == verA[j] && colrow[j] == i) {
                const double m1 = bidm1[i], m2 = bidm2[i];
                const int prev = pA[j];
                pA[j] = i;
                verA[j] = verA[j] + 1;
                vA[j] -= (m2 - m1);          // v only decreases (diff >= 0)
                u[i] = m2;
                assigned[i] = 1;
                if (prev >= 0) assigned[prev] = 0;
            }
        }
        __syncthreads();
        if (tid < NT && !assigned[tid]) { const int k = atomicAdd(&pcnt, 1); plist[k] = tid; }
        __syncthreads();
        const int np = pcnt;
        if (np == 0) break;
        if (np >= prev_np) { if (++stall >= STALLCAP) break; }
        else               { stall = 0; }
        prev_np = np;
        for (int idx = wv; idx < np; idx += NWAVE) {
            const int i = plist[idx];
            const float* rp = C + (size_t)i * QQ;
            float rowv[SLOTS];
            #pragma unroll
            for (int k = 0; k < SLOTS; ++k) { const int c = qq + 64*k; rowv[k] = (c < QQ) ? rp[c] : 0.f; }
            double m1 = INFINITY, m2 = INFINITY; int j1 = QQ;
            #pragma unroll
            for (int k = 0; k < SLOTS; ++k) {
                const int c = qq + 64 * k;
                if (c < QQ) {
                    const double key = (double)rowv[k] - vA[c];
                    if (key < m1)      { m2 = m1; m1 = key; j1 = c; }
                    else if (key < m2) { m2 = key; }
                }
            }
            int winlane;
            const unsigned long long kminv = wave_min_key64(f64_key(m1), &winlane);
            // global 2nd-min = min over (winner's m2, everyone else's m1)
            const unsigned long long c2 = (qq == winlane) ? f64_key(m2) : f64_key(m1);
            const unsigned long long k2minv = wave_min_key64_val(c2);
            const int jwin = __shfl(j1, winlane);
            if (qq == 0) {
                bidm1[i] = key_f64(kminv); bidm2[i] = key_f64(k2minv); bidj[i] = jwin;
                bidver[i] = verA[jwin];
                u[i] = key_f64(kminv);       // feasible forever (v only dec.)
            }
        }
        __syncthreads();
    }

    if (wv != 0) return;   // ============ wave 0 only below; no barriers ====
    const int lane = qq;

    // collect drained rows (uniform control flow)
    int nd = 0;
    for (int i = 0; i < NT; ++i) {
        if (!assigned[i]) { if (lane == 0) djkA[nd] = i; ++nd; }
    }

    double v_[SLOTS], minv_[SLOTS];
    int p_[SLOTS];
    #pragma unroll
    for (int k = 0; k < SLOTS; ++k) {
        const int c = lane + 64 * k;
        v_[k] = (c < QQ) ? vA[c] : 0.0;
        p_[k] = (c < QQ) ? pA[c] : -1;
    }

    // ================= Dijkstra SAP (exact, R16 structure) =================
    float rowv[SLOTS];
    for (int ii = 0; ii < nd; ++ii) {
        const int i = djkA[ii];
        #pragma unroll
        for (int k = 0; k < SLOTS; ++k) minv_[k] = INFINITY;
        unsigned usedm = 0;
        int j0 = -1;
        double ui0 = u[i];
        {
            const float* rp = C + (size_t)i * QQ;
            #pragma unroll
            for (int k = 0; k < SLOTS; ++k) { const int c = lane + 64*k; rowv[k] = (c < QQ) ? rp[c] : 0.f; }
        }
        int j1, i1;

        for (;;) {
            if (j0 >= 0 && (j0 & 63) == lane) usedm |= 1u << (j0 >> 6);

            double bestv = INFINITY; int bestc = QQ;
            #pragma unroll
            for (int k = 0; k < SLOTS; ++k) {
                const int c = lane + 64 * k;
                if (c < QQ && !((usedm >> k) & 1u)) {
                    const double cur = ((double)rowv[k] - ui0) - v_[k];
                    if (cur < minv_[k]) { minv_[k] = cur; wayA[c] = j0; }
                    if (minv_[k] < bestv) { bestv = minv_[k]; bestc = c; }
                }
            }
            int winlane;
            const unsigned long long kminv = wave_min_key64(f64_key(bestv), &winlane);
            const double delta = key_f64(kminv);
            j1 = __shfl(bestc, winlane);

            {   // i1 = p[j1] via register select + shuffle
                const int slot = j1 >> 6, lj = j1 & 63;
                int myp = p_[0];
                #pragma unroll
                for (int k = 1; k < SLOTS; ++k) if (slot == k) myp = p_[k];
                i1 = __shfl(myp, lj);
            }

            double ui_next = 0.0;
            float rown[SLOTS];
            if (i1 >= 0) {      // prefetch next row (not in tree -> u stable)
                ui_next = u[i1];
                const float* rp = C + (size_t)i1 * QQ;
                #pragma unroll
                for (int k = 0; k < SLOTS; ++k) { const int c = lane + 64*k; rown[k] = (c < QQ) ? rp[c] : 0.f; }
            }

            #pragma unroll
            for (int k = 0; k < SLOTS; ++k) {
                const int c = lane + 64 * k;
                if (c < QQ) {
                    if ((usedm >> k) & 1u) { v_[k] -= delta; u[p_[k]] += delta; }
                    else                     minv_[k] -= delta;
                }
            }
            if (lane == 0) u[i] += delta;

            j0 = j1;
            if (i1 < 0) break;
            ui0 = ui_next;
            #pragma unroll
            for (int k = 0; k < SLOTS; ++k) rowv[k] = rown[k];
        }

        if (lane == 0) {        // augment along way chain
            int jj = j1;
            while (jj >= 0) {
                const int pr = wayA[jj];
                pA[jj] = (pr < 0) ? i : pA[pr];
                jj = pr;
            }
        }
        #pragma unroll
        for (int k = 0; k < SLOTS; ++k) {
            const int c = lane + 64 * k;
            p_[k] = (c < QQ) ? pA[c] : -1;
        }
    }

    // ---- emit in increasing query order (== reference's stable argsort) ----
    #pragma unroll
    for (int k = 0; k < SLOTS; ++k) {
        const int c = lane + 64 * k;
        if (c < QQ) { const int t = pA[c]; if (t >= 0) c4r[t] = c; }
    }
    for (int t = lane; t < NT; t += 64) {
        const int c = c4r[t];
        int rank = 0;
        for (int t2 = 0; t2 < NT; ++t2) rank += (c4r[t2] < c) ? 1 : 0;
        rows_out[b * NT + rank] = c;
        cols_out[b * NT + rank] = t;
    }
}

extern "C" void kernel_launch(void* const* d_in, const int* in_sizes, int n_in,
                              void* d_out, int out_size, void* d_ws, size_t ws_size,
                              hipStream_t stream) {
    (void)in_sizes; (void)n_in; (void)out_size; (void)ws_size;
    const float* logits  = (const float*)d_in[0];
    const float* pboxes  = (const float*)d_in[1];
    const int*   tlabels = (const int*)d_in[2];
    const float* tboxes  = (const float*)d_in[3];
    float* cost = (float*)d_ws;                          // 12,288,000 B
    float* pm1  = cost + (size_t)BB * NT * QQ;           // +204,800 B
    float* pm2  = pm1  + (size_t)BB * NT * NTILE;        // +204,800 B
    int*   pmj  = (int*)(pm2 + (size_t)BB * NT * NTILE); // +204,800 B
    int*   out  = (int*)d_out;

    phasea_kernel<<<dim3(BB * NTILE), NTHR, 0, stream>>>(
        logits, pboxes, tlabels, tboxes, cost, pm1, pm2, pmj);
    solver_kernel<<<dim3(BB), NTHR, 0, stream>>>(
        cost, pm1, pm2, pmj, out, out + BB * NT);
}